// Round 2
// baseline (812.212 us; speedup 1.0000x reference)
//
#include <hip/hip_runtime.h>
#include <cmath>

#define DM 512
#define DS 256
#define NL 4
#define BATCH 8
#define SEQ 2048
#define MROWS (BATCH*SEQ)   // 16384
#define LCH 32
#define NCH 64              // LCH*NCH == SEQ

typedef unsigned short ushort_t;
typedef unsigned int uint_t;
typedef unsigned long long ull_t;
typedef __attribute__((ext_vector_type(8))) short short8;
typedef __attribute__((ext_vector_type(4))) float floatx4;

__device__ __forceinline__ float sigmoidf_(float v) { return 1.0f / (1.0f + __expf(-v)); }

__device__ __forceinline__ ushort_t f2bf(float f) {
    union { float f; unsigned int u; } c; c.f = f;
    unsigned int u = c.u;
    u += 0x7fffu + ((u >> 16) & 1u);          // RNE
    return (ushort_t)(u >> 16);
}
__device__ __forceinline__ float bf2f(uint_t h) {
    union { unsigned int u; float f; } c; c.u = (h & 0xffffu) << 16; return c.f;
}
__device__ __forceinline__ uint_t pack2(float a, float b) {
    return (uint_t)f2bf(a) | ((uint_t)f2bf(b) << 16);
}

#define AS1 __attribute__((address_space(1)))
#define AS3 __attribute__((address_space(3)))
__device__ __forceinline__ void gl_lds16(const void* g, void* l) {
    __builtin_amdgcn_global_load_lds((const AS1 uint_t*)g, (AS3 uint_t*)l, 16, 0, 0);
}

// All GEMM arguments in one struct: no positional-arity pitfalls.
struct GemmArgs {
    const ushort_t* A;       // [M,K] bf16
    const ushort_t* Wa;      // [N,K] bf16
    const ushort_t* Wb;      // [N,K] bf16 (DUAL only)
    const ushort_t* xbf_in;  // EPI2/EPI3: bf16 x
    const float* gam;        // EPI1
    const float* Dv;         // EPI2
    float* of32;             // EPI4
    ushort_t* obf;           // EPI0..3
    const float* resp;       // EPI3
    int K;
    int N;
    int layer;
};

// ---------------------------------------------------------------------------
// bf16 MFMA GEMM, double-buffered async global->LDS staging, LDS-transpose
// epilogue. O = A[M,K] @ W[N,K]^T. EPI:
//  0: encoder  -> obf = bf16(acc)
//  1: Bu       -> obf = bf16(acc * gam[col>>1])        (interleaved re/im cols)
//  2: z        -> obf = bf16(acc + Dv[col]*bf2f(xbf_in[row,col]))
//  3: GLU dual -> obf = bf16(bf2f(xbf_in) + sigmoid(resp[l])*acc0*sigmoid(acc1))
//  4: plain    -> of32 = acc   (decoder, BN=64, direct store)
// launch_bounds 3 (single) / 2 (dual): dual needs >=128 VGPR for acc alone —
// bound 3 forces spills (R13: VGPR 84, +27MB scratch traffic, 28->55us).
// ---------------------------------------------------------------------------
#define PREFETCH_TILE(it_, buf_)                                                        \
    do {                                                                                \
        const size_t kb_ = (size_t)(it_) * 64;                                          \
        char* dst_ = smem + (buf_) * HALF;                                              \
        gl_lds16(Ap + (size_t)(wid * 16 + lrow) * Kb + kb_, dst_ + wid * 1024);         \
        gl_lds16(Ap + (size_t)((wid + 4) * 16 + lrow) * Kb + kb_,                       \
                 dst_ + (wid + 4) * 1024);                                              \
        gl_lds16(B0p + (size_t)(wid * 16 + lrow) * Kb + kb_, dst_ + AB + wid * 1024);   \
        if constexpr (BN == 128) {                                                      \
            gl_lds16(B0p + (size_t)((wid + 4) * 16 + lrow) * Kb + kb_,                  \
                     dst_ + AB + (wid + 4) * 1024);                                     \
        }                                                                               \
        if constexpr (DUAL) {                                                           \
            gl_lds16(B1p + (size_t)(wid * 16 + lrow) * Kb + kb_,                        \
                     dst_ + AB + BB + wid * 1024);                                      \
            if constexpr (BN == 128) {                                                  \
                gl_lds16(B1p + (size_t)((wid + 4) * 16 + lrow) * Kb + kb_,              \
                         dst_ + AB + BB + (wid + 4) * 1024);                            \
            }                                                                           \
        }                                                                               \
    } while (0)

template<int BN, int EPI, int DUAL>
__launch_bounds__(256, DUAL ? 2 : 3)
__global__ void mgemm(const GemmArgs p) {
    constexpr int BM = 128;
    constexpr int MT = (BN == 128) ? 4 : 2;
    constexpr int NT = 4;
    constexpr int WROWS = MT * 16;
    constexpr int AB = 8192;                         // A stage bytes (128 x 64B)
    constexpr int BB = (BN == 128) ? 8192 : 4096;
    constexpr int B1B = DUAL ? BB : 0;
    constexpr int HALF = AB + BB + B1B;              // one pipeline stage
    constexpr int EPB = (EPI == 4) ? 0 : 32 * 132 * 4;
    constexpr int SMB = (2 * HALF > EPB) ? 2 * HALF : EPB;
    __shared__ __align__(16) char smem[SMB];

    const int K = p.K, N = p.N;
    const int tid = threadIdx.x, lane = tid & 63, wid = tid >> 6;
    const int wm = (BN == 128) ? (wid & 1) : wid;
    const int wn = (BN == 128) ? (wid >> 1) : 0;
    const int m0 = blockIdx.x * BM, n0 = blockIdx.y * BN;
    const int q = lane >> 4, r16 = lane & 15;
    const int lrow = lane >> 2;
    const size_t Kb = (size_t)K * 2;                 // row bytes
    const char* Ap  = (const char*)p.A  + (size_t)m0 * Kb + (lane & 3) * 16;
    const char* B0p = (const char*)p.Wa + (size_t)n0 * Kb + (lane & 3) * 16;
    const char* B1p = (const char*)p.Wb + (size_t)n0 * Kb + (lane & 3) * 16;

    floatx4 acc0[MT][NT] = {};
    floatx4 acc1[DUAL ? MT : 1][DUAL ? NT : 1] = {};

    const int iters = K >> 5;
    PREFETCH_TILE(0, 0);
    for (int it = 0; it < iters; ++it) {
        __syncthreads();
        if (it + 1 < iters) PREFETCH_TILE(it + 1, (it + 1) & 1);
        const ushort_t* As  = (const ushort_t*)(smem + (it & 1) * HALF);
        const ushort_t* Bs0 = (const ushort_t*)(smem + (it & 1) * HALF + AB);
        const ushort_t* Bs1 = (const ushort_t*)(smem + (it & 1) * HALF + AB + BB);

        short8 af[MT], b0[NT], b1[DUAL ? NT : 1];
#pragma unroll
        for (int i = 0; i < MT; ++i)
            af[i] = *(const short8*)&As[(wm * WROWS + i * 16 + r16) * 32 + q * 8];
#pragma unroll
        for (int j = 0; j < NT; ++j) {
            b0[j] = *(const short8*)&Bs0[(wn * 64 + j * 16 + r16) * 32 + q * 8];
            if constexpr (DUAL)
                b1[j] = *(const short8*)&Bs1[(wn * 64 + j * 16 + r16) * 32 + q * 8];
        }
#pragma unroll
        for (int i = 0; i < MT; ++i)
#pragma unroll
            for (int j = 0; j < NT; ++j) {
                acc0[i][j] = __builtin_amdgcn_mfma_f32_16x16x32_bf16(af[i], b0[j], acc0[i][j], 0, 0, 0);
                if constexpr (DUAL)
                    acc1[i][j] = __builtin_amdgcn_mfma_f32_16x16x32_bf16(af[i], b1[j], acc1[i][j], 0, 0, 0);
            }
    }

    if constexpr (EPI == 4) {
#pragma unroll
        for (int i = 0; i < MT; ++i)
#pragma unroll
            for (int j = 0; j < NT; ++j)
#pragma unroll
                for (int rr = 0; rr < 4; ++rr) {
                    const int row = m0 + wm * WROWS + i * 16 + q * 4 + rr;
                    const int col = wn * 64 + j * 16 + r16;
                    p.of32[(size_t)row * N + col] = acc0[i][j][rr];
                }
        return;
    } else {
        float* eps = (float*)smem;                    // [32][132]
        float rsv = 0.f;
        if constexpr (EPI == 3) rsv = sigmoidf_(p.resp[p.layer]);

#pragma unroll
        for (int i = 0; i < MT; ++i) {
            __syncthreads();
#pragma unroll
            for (int j = 0; j < NT; ++j) {
                const int colt = wn * 64 + j * 16 + r16;
#pragma unroll
                for (int rr = 0; rr < 4; ++rr) {
                    float v = acc0[i][j][rr];
                    if constexpr (EPI == 1) v *= p.gam[(n0 + colt) >> 1];
                    if constexpr (EPI == 3) v = rsv * v * sigmoidf_(acc1[i][j][rr]);
                    eps[(wm * 16 + q * 4 + rr) * 132 + colt] = v;
                }
            }
            __syncthreads();
            const int row_r = tid >> 3, colg = (tid & 7) * 16;
            const int grow = m0 + (row_r >> 4) * 64 + i * 16 + (row_r & 15);
            const int gcol = n0 + colg;
            float4 f[4];
#pragma unroll
            for (int c = 0; c < 4; ++c) f[c] = *(float4*)&eps[row_r * 132 + colg + c * 4];
            const size_t ob = (size_t)grow * N + gcol;

            if constexpr (EPI == 2) {
                uint_t xp[8];
                *(uint4*)(xp)     = *(const uint4*)(p.xbf_in + ob);
                *(uint4*)(xp + 4) = *(const uint4*)(p.xbf_in + ob + 8);
#pragma unroll
                for (int c = 0; c < 4; ++c) {
                    float4 dv = *(const float4*)(p.Dv + gcol + c * 4);
                    f[c].x += dv.x * bf2f(xp[2 * c]);
                    f[c].y += dv.y * bf2f(xp[2 * c] >> 16);
                    f[c].z += dv.z * bf2f(xp[2 * c + 1]);
                    f[c].w += dv.w * bf2f(xp[2 * c + 1] >> 16);
                }
            } else if constexpr (EPI == 3) {
                uint_t xp[8];
                *(uint4*)(xp)     = *(const uint4*)(p.xbf_in + ob);
                *(uint4*)(xp + 4) = *(const uint4*)(p.xbf_in + ob + 8);
#pragma unroll
                for (int c = 0; c < 4; ++c) {
                    f[c].x += bf2f(xp[2 * c]);
                    f[c].y += bf2f(xp[2 * c] >> 16);
                    f[c].z += bf2f(xp[2 * c + 1]);
                    f[c].w += bf2f(xp[2 * c + 1] >> 16);
                }
            }
            uint4 p0, p1;
            p0.x = pack2(f[0].x, f[0].y); p0.y = pack2(f[0].z, f[0].w);
            p0.z = pack2(f[1].x, f[1].y); p0.w = pack2(f[1].z, f[1].w);
            p1.x = pack2(f[2].x, f[2].y); p1.y = pack2(f[2].z, f[2].w);
            p1.z = pack2(f[3].x, f[3].y); p1.w = pack2(f[3].z, f[3].w);
            *(uint4*)(p.obf + ob) = p0;
            *(uint4*)(p.obf + ob + 8) = p1;
        }
    }
}

// ---------------------------------------------------------------------------
// Single prep kernel: all weight bf16 packing + u cast + lambda/gamma tables
// + scan flag/ticket zeroing.
// ---------------------------------------------------------------------------
__global__ void prep_all(const float* __restrict__ u, const float* __restrict__ enc,
                         const float* __restrict__ dec, const float* __restrict__ nu,
                         const float* __restrict__ th,
                         const float* __restrict__ Bre, const float* __restrict__ Bim,
                         const float* __restrict__ Cre, const float* __restrict__ Cim,
                         const float* __restrict__ W1, const float* __restrict__ W2,
                         ushort_t* __restrict__ WBb, ushort_t* __restrict__ Wzb,
                         ushort_t* __restrict__ W1b, ushort_t* __restrict__ W2b,
                         ushort_t* __restrict__ encb, ushort_t* __restrict__ decb,
                         ushort_t* __restrict__ ubf,
                         float* __restrict__ lre, float* __restrict__ lim,
                         float* __restrict__ gm,
                         ull_t* __restrict__ msk, int* __restrict__ tkt) {
    const int idx = blockIdx.x * 256 + threadIdx.x;   // 0..1M-1
    const int k = idx & 511, n = (idx >> 9) & 511, l = idx >> 18;
    {
        const int s = n >> 1, part = n & 1;
        const float* src = part ? Bim : Bre;
        WBb[idx] = f2bf(src[((size_t)l * DS + s) * DM + k]);
    }
    {
        const int s = k >> 1, part = k & 1;
        float v = part ? -Cim[((size_t)l * DM + n) * DS + s]
                       :  Cre[((size_t)l * DM + n) * DS + s];
        Wzb[idx] = f2bf(v);
    }
    W1b[idx] = f2bf(W1[idx]);
    W2b[idx] = f2bf(W2[idx]);
    ubf[idx] = f2bf(u[idx]);
    if (idx < DM * 64) { encb[idx] = f2bf(enc[idx]); decb[idx] = f2bf(dec[idx]); }
    if (idx < NL * DS) {
        float a = expf(-expf(nu[idx])), t = expf(th[idx]);
        lre[idx] = a * cosf(t);
        lim[idx] = a * sinf(t);
        gm[idx] = sqrtf(fmaxf(0.f, 1.f - a * a));
    }
    if (idx < NL * BATCH) msk[idx] = 0ull;
    if (idx < NL) tkt[idx] = 0;
}

// ---------------------------------------------------------------------------
// Single-pass decoupled-lookback scan, LDS-stash variant.
// 512 blocks (8 batch x 64 chunks of 32). R1 post-mortem: keeping h[32] in
// registers spilled to scratch (VGPR_Count=52 < 64 floats of state) ->
// 107us/dispatch of flat-scratch latency. Fix: keep ONLY the 2-float running
// state; stash the raw Bu chunk in LDS (32KB) during pass A, then re-run the
// recurrence from the corrected initial state in pass B reading LDS
// (stride-1, 2 lanes/bank = conflict-free). Identical math to R1.
// - atomic ticket reassigns chunks in dispatch order -> no dependence on
//   workgroup dispatch order (G16-safe forward progress).
// - per-batch release-flag bitmask; consumers acquire-load the mask, then
//   look back over predecessors' LOCAL chunk-ends.
// - |lam|<=0.95 -> |lam^32|<=0.194 -> lookback truncated at depth 12
//   (truncation error < 1e-8, far below bf16 noise).
// ---------------------------------------------------------------------------
__global__ __launch_bounds__(256) void scan_fused(
        const uint_t* __restrict__ Bu, const float* __restrict__ lre_,
        const float* __restrict__ lim_, float* __restrict__ carry,
        ull_t* __restrict__ msk, int* __restrict__ tkt,
        uint_t* __restrict__ h) {
    __shared__ uint_t stash[LCH * DS];   // 32 KB raw Bu chunk
    __shared__ int vblk_s;
    if (threadIdx.x == 0) vblk_s = atomicAdd(tkt, 1);
    __syncthreads();
    const int blk = vblk_s;
    const int s = threadIdx.x;
    const int b = blk >> 6, c = blk & 63;
    const float lre = lre_[s], lim = lim_[s];

    // pass A: stream Bu -> LDS stash, keep only running local state
    float xr = 0.f, xi = 0.f;
    const size_t base = ((size_t)b * SEQ + (size_t)c * LCH) * DS + s;
#pragma unroll 8
    for (int i = 0; i < LCH; ++i) {
        uint_t uu = Bu[base + (size_t)i * DS];
        stash[i * DS + s] = uu;
        float br = bf2f(uu), bi = bf2f(uu >> 16);
        float nr = fmaf(lre, xr, fmaf(-lim, xi, br));
        float ni = fmaf(lre, xi, fmaf(lim, xr, bi));
        xr = nr; xi = ni;
    }

    // publish local end, release flag (verified machinery from R1)
    const size_t cb = (size_t)blk * 512 + s;
    carry[cb] = xr; carry[cb + DS] = xi;
    __syncthreads();
    if (threadIdx.x == 0) {
        __threadfence();
        __hip_atomic_fetch_or(&msk[b], 1ull << c, __ATOMIC_RELEASE, __HIP_MEMORY_SCOPE_AGENT);
    }

    // lookback: g = state at end of chunk c-1 (truncated geometric sum)
    float gre = 0.f, gim = 0.f;
    if (c > 0) {
        float are = lre, aim = lim;          // lam^32 (5 squarings)
#pragma unroll
        for (int t = 0; t < 5; ++t) {
            float nr = are * are - aim * aim, ni = 2.f * are * aim;
            are = nr; aim = ni;
        }
        const int depth = (c < 12) ? c : 12;
        const ull_t need = ((1ull << depth) - 1ull) << (c - depth);
        while ((__hip_atomic_load(&msk[b], __ATOMIC_ACQUIRE, __HIP_MEMORY_SCOPE_AGENT)
                & need) != need) {
            __builtin_amdgcn_s_sleep(2);
        }
        float pwr = 1.f, pwi = 0.f;
        for (int j = c - 1; j >= c - depth; --j) {
            const size_t jb = (size_t)(b * NCH + j) * 512 + s;
            float er = carry[jb], ei = carry[jb + DS];
            gre = fmaf(pwr, er, fmaf(-pwi, ei, gre));
            gim = fmaf(pwr, ei, fmaf(pwi, er, gim));
            float nr = pwr * are - pwi * aim, ni = pwr * aim + pwi * are;
            pwr = nr; pwi = ni;
        }
    }

    // pass B: recompute chain from g out of the LDS stash, write h
    float hr = gre, hi = gim;
#pragma unroll 8
    for (int i = 0; i < LCH; ++i) {
        uint_t uu = stash[i * DS + s];
        float br = bf2f(uu), bi = bf2f(uu >> 16);
        float nr = fmaf(lre, hr, fmaf(-lim, hi, br));
        float ni = fmaf(lre, hi, fmaf(lim, hr, bi));
        hr = nr; hi = ni;
        h[base + (size_t)i * DS] = pack2(hr, hi);
    }
}

// ---------------------------------------------------------------------------
extern "C" void kernel_launch(void* const* d_in, const int* in_sizes, int n_in,
                              void* d_out, int out_size, void* d_ws, size_t ws_size,
                              hipStream_t stream) {
    const float* u   = (const float*)d_in[0];
    const float* enc = (const float*)d_in[1];
    const float* dec = (const float*)d_in[2];
    const float* nu  = (const float*)d_in[3];
    const float* th  = (const float*)d_in[4];
    const float* Bre = (const float*)d_in[5];
    const float* Bim = (const float*)d_in[6];
    const float* Cre = (const float*)d_in[7];
    const float* Cim = (const float*)d_in[8];
    const float* Dp  = (const float*)d_in[9];
    const float* W1  = (const float*)d_in[10];
    const float* W2  = (const float*)d_in[11];
    const float* res = (const float*)d_in[12];
    float* out = (float*)d_out;

    const size_t MD = (size_t)MROWS * DM;
    float* carry = (float*)d_ws;                         // [8*64,512] fp32
    float* lre  = carry + (size_t)BATCH * NCH * 512;
    float* lim  = lre + NL * DS;
    float* gmt  = lim + NL * DS;
    ull_t* msk  = (ull_t*)(gmt + NL * DS);               // [NL][BATCH] flags
    int*   tkt  = (int*)(msk + NL * BATCH);              // [NL] tickets
    ushort_t* xbf  = (ushort_t*)(tkt + NL);              // bf16 [16384,512] each:
    ushort_t* Bubf = xbf + MD;
    ushort_t* hbf  = Bubf + MD;
    ushort_t* zbf  = hbf + MD;
    ushort_t* ubf  = zbf;                                // alias: z written after u consumed
    ushort_t* WBb  = zbf + MD;                           // weights, 4x512x512 bf16 each:
    ushort_t* Wzb  = WBb + (size_t)NL * DM * DM;
    ushort_t* W1b  = Wzb + (size_t)NL * DM * DM;
    ushort_t* W2b  = W1b + (size_t)NL * DM * DM;
    ushort_t* encb = W2b + (size_t)NL * DM * DM;         // 512x64
    ushort_t* decb = encb + DM * 64;                     // 64x512

    prep_all<<<NL * DM * DM / 256, 256, 0, stream>>>(
        u, enc, dec, nu, th, Bre, Bim, Cre, Cim, W1, W2,
        WBb, Wzb, W1b, W2b, encb, decb, ubf, lre, lim, gmt, msk, tkt);

    const dim3 gFull(MROWS / 128, DM / 128);

    // encoder: xbf = bf16(u @ enc^T)
    {
        GemmArgs a = {};
        a.A = ubf; a.Wa = encb; a.K = 64; a.N = DM;
        a.obf = xbf;
        mgemm<128, 0, 0><<<gFull, 256, 0, stream>>>(a);
    }

    for (int k = 0; k < NL; ++k) {
        {   // Bu (interleaved re/im cols, gamma-scaled) -> Bubf
            GemmArgs a = {};
            a.A = xbf; a.Wa = WBb + (size_t)k * DM * DM; a.K = DM; a.N = DM;
            a.obf = Bubf; a.gam = gmt + k * DS;
            mgemm<128, 1, 0><<<gFull, 256, 0, stream>>>(a);
        }
        scan_fused<<<BATCH * NCH, 256, 0, stream>>>(
            (const uint_t*)Bubf, lre + k * DS, lim + k * DS, carry,
            msk + (size_t)k * BATCH, tkt + k, (uint_t*)hbf);
        {   // z = Re(h @ C^T) + D*x  -> zbf
            GemmArgs a = {};
            a.A = hbf; a.Wa = Wzb + (size_t)k * DM * DM; a.K = DM; a.N = DM;
            a.obf = zbf; a.xbf_in = xbf; a.Dv = Dp + k * DM;
            mgemm<128, 2, 0><<<gFull, 256, 0, stream>>>(a);
        }
        {   // xbf += sig(res)*[(z@W1^T)*sigmoid(z@W2^T)]   (bf16 RMW)
            GemmArgs a = {};
            a.A = zbf; a.Wa = W1b + (size_t)k * DM * DM; a.Wb = W2b + (size_t)k * DM * DM;
            a.K = DM; a.N = DM;
            a.obf = xbf; a.xbf_in = xbf; a.resp = res; a.layer = k;
            mgemm<128, 3, 1><<<gFull, 256, 0, stream>>>(a);
        }
    }
    {   // decoder: out = x @ dec^T
        GemmArgs a = {};
        a.A = xbf; a.Wa = decb; a.K = DM; a.N = 64;
        a.of32 = out;
        mgemm<64, 4, 0><<<dim3(MROWS / 128, 1), 256, 0, stream>>>(a);
    }
}

// Round 3
// 388.477 us; speedup vs baseline: 2.0908x; 2.0908x over previous
//
#include <hip/hip_runtime.h>
#include <cmath>

#define DM 512
#define DS 256
#define NL 4
#define BATCH 8
#define SEQ 2048
#define MROWS (BATCH*SEQ)   // 16384
#define LCH 32
#define NCH 64              // LCH*NCH == SEQ

typedef unsigned short ushort_t;
typedef unsigned int uint_t;
typedef __attribute__((ext_vector_type(8))) short short8;
typedef __attribute__((ext_vector_type(4))) float floatx4;

__device__ __forceinline__ float sigmoidf_(float v) { return 1.0f / (1.0f + __expf(-v)); }

__device__ __forceinline__ ushort_t f2bf(float f) {
    union { float f; unsigned int u; } c; c.f = f;
    unsigned int u = c.u;
    u += 0x7fffu + ((u >> 16) & 1u);          // RNE
    return (ushort_t)(u >> 16);
}
__device__ __forceinline__ float bf2f(uint_t h) {
    union { unsigned int u; float f; } c; c.u = (h & 0xffffu) << 16; return c.f;
}
__device__ __forceinline__ uint_t pack2(float a, float b) {
    return (uint_t)f2bf(a) | ((uint_t)f2bf(b) << 16);
}

#define AS1 __attribute__((address_space(1)))
#define AS3 __attribute__((address_space(3)))
__device__ __forceinline__ void gl_lds16(const void* g, void* l) {
    __builtin_amdgcn_global_load_lds((const AS1 uint_t*)g, (AS3 uint_t*)l, 16, 0, 0);
}

// All GEMM arguments in one struct: no positional-arity pitfalls.
struct GemmArgs {
    const ushort_t* A;       // [M,K] bf16
    const ushort_t* Wa;      // [N,K] bf16
    const ushort_t* Wb;      // [N,K] bf16 (DUAL only)
    const ushort_t* xbf_in;  // EPI2/EPI3: bf16 x
    const float* gam;        // EPI1
    const float* Dv;         // EPI2
    float* of32;             // EPI4
    ushort_t* obf;           // EPI0..3
    const float* resp;       // EPI3
    int K;
    int N;
    int layer;
};

// ---------------------------------------------------------------------------
// bf16 MFMA GEMM, double-buffered async global->LDS staging, LDS-transpose
// epilogue. O = A[M,K] @ W[N,K]^T. EPI:
//  0: encoder  -> obf = bf16(acc)
//  1: Bu       -> obf = bf16(acc * gam[col>>1])        (interleaved re/im cols)
//  2: z        -> obf = bf16(acc + Dv[col]*bf2f(xbf_in[row,col]))
//  3: GLU dual -> obf = bf16(bf2f(xbf_in) + sigmoid(resp[l])*acc0*sigmoid(acc1))
//  4: plain    -> of32 = acc   (decoder, BN=64, direct store)
// launch_bounds 3 (single) / 2 (dual): dual needs >=128 VGPR for acc alone —
// bound 3 forces spills (R13: VGPR 84, +27MB scratch traffic, 28->55us).
// T1 XCD swizzle (R3): dispatch round-robins XCDs; remap so each XCD gets a
// contiguous 16-wide x-chunk across ALL y -> A-panel (2MB) stays in its 4MB
// L2 across the 4 y-panels instead of being refetched from HBM 4x.
// Requires gridDim.x == 128 (both launch shapes here). Bijective.
// ---------------------------------------------------------------------------
#define PREFETCH_TILE(it_, buf_)                                                        \
    do {                                                                                \
        const size_t kb_ = (size_t)(it_) * 64;                                          \
        char* dst_ = smem + (buf_) * HALF;                                              \
        gl_lds16(Ap + (size_t)(wid * 16 + lrow) * Kb + kb_, dst_ + wid * 1024);         \
        gl_lds16(Ap + (size_t)((wid + 4) * 16 + lrow) * Kb + kb_,                       \
                 dst_ + (wid + 4) * 1024);                                              \
        gl_lds16(B0p + (size_t)(wid * 16 + lrow) * Kb + kb_, dst_ + AB + wid * 1024);   \
        if constexpr (BN == 128) {                                                      \
            gl_lds16(B0p + (size_t)((wid + 4) * 16 + lrow) * Kb + kb_,                  \
                     dst_ + AB + (wid + 4) * 1024);                                     \
        }                                                                               \
        if constexpr (DUAL) {                                                           \
            gl_lds16(B1p + (size_t)(wid * 16 + lrow) * Kb + kb_,                        \
                     dst_ + AB + BB + wid * 1024);                                      \
            if constexpr (BN == 128) {                                                  \
                gl_lds16(B1p + (size_t)((wid + 4) * 16 + lrow) * Kb + kb_,              \
                         dst_ + AB + BB + (wid + 4) * 1024);                            \
            }                                                                           \
        }                                                                               \
    } while (0)

template<int BN, int EPI, int DUAL>
__launch_bounds__(256, DUAL ? 2 : 3)
__global__ void mgemm(const GemmArgs p) {
    constexpr int BM = 128;
    constexpr int MT = (BN == 128) ? 4 : 2;
    constexpr int NT = 4;
    constexpr int WROWS = MT * 16;
    constexpr int AB = 8192;                         // A stage bytes (128 x 64B)
    constexpr int BB = (BN == 128) ? 8192 : 4096;
    constexpr int B1B = DUAL ? BB : 0;
    constexpr int HALF = AB + BB + B1B;              // one pipeline stage
    constexpr int EPB = (EPI == 4) ? 0 : 32 * 132 * 4;
    constexpr int SMB = (2 * HALF > EPB) ? 2 * HALF : EPB;
    __shared__ __align__(16) char smem[SMB];

    const int K = p.K, N = p.N;
    const int tid = threadIdx.x, lane = tid & 63, wid = tid >> 6;
    const int wm = (BN == 128) ? (wid & 1) : wid;
    const int wn = (BN == 128) ? (wid >> 1) : 0;

    // T1 XCD-chunked swizzle (gridDim.x == 128, 128 % 8 == 0 -> bijective)
    const int flat = blockIdx.y * 128 + blockIdx.x;
    const int xcd = flat & 7, sidx = flat >> 3;
    const int bx = xcd * 16 + (sidx & 15);
    const int by = sidx >> 4;

    const int m0 = bx * BM, n0 = by * BN;
    const int q = lane >> 4, r16 = lane & 15;
    const int lrow = lane >> 2;
    const size_t Kb = (size_t)K * 2;                 // row bytes
    const char* Ap  = (const char*)p.A  + (size_t)m0 * Kb + (lane & 3) * 16;
    const char* B0p = (const char*)p.Wa + (size_t)n0 * Kb + (lane & 3) * 16;
    const char* B1p = (const char*)p.Wb + (size_t)n0 * Kb + (lane & 3) * 16;

    floatx4 acc0[MT][NT] = {};
    floatx4 acc1[DUAL ? MT : 1][DUAL ? NT : 1] = {};

    const int iters = K >> 5;
    PREFETCH_TILE(0, 0);
    for (int it = 0; it < iters; ++it) {
        __syncthreads();
        if (it + 1 < iters) PREFETCH_TILE(it + 1, (it + 1) & 1);
        const ushort_t* As  = (const ushort_t*)(smem + (it & 1) * HALF);
        const ushort_t* Bs0 = (const ushort_t*)(smem + (it & 1) * HALF + AB);
        const ushort_t* Bs1 = (const ushort_t*)(smem + (it & 1) * HALF + AB + BB);

        short8 af[MT], b0[NT], b1[DUAL ? NT : 1];
#pragma unroll
        for (int i = 0; i < MT; ++i)
            af[i] = *(const short8*)&As[(wm * WROWS + i * 16 + r16) * 32 + q * 8];
#pragma unroll
        for (int j = 0; j < NT; ++j) {
            b0[j] = *(const short8*)&Bs0[(wn * 64 + j * 16 + r16) * 32 + q * 8];
            if constexpr (DUAL)
                b1[j] = *(const short8*)&Bs1[(wn * 64 + j * 16 + r16) * 32 + q * 8];
        }
#pragma unroll
        for (int i = 0; i < MT; ++i)
#pragma unroll
            for (int j = 0; j < NT; ++j) {
                acc0[i][j] = __builtin_amdgcn_mfma_f32_16x16x32_bf16(af[i], b0[j], acc0[i][j], 0, 0, 0);
                if constexpr (DUAL)
                    acc1[i][j] = __builtin_amdgcn_mfma_f32_16x16x32_bf16(af[i], b1[j], acc1[i][j], 0, 0, 0);
            }
    }

    if constexpr (EPI == 4) {
#pragma unroll
        for (int i = 0; i < MT; ++i)
#pragma unroll
            for (int j = 0; j < NT; ++j)
#pragma unroll
                for (int rr = 0; rr < 4; ++rr) {
                    const int row = m0 + wm * WROWS + i * 16 + q * 4 + rr;
                    const int col = wn * 64 + j * 16 + r16;
                    p.of32[(size_t)row * N + col] = acc0[i][j][rr];
                }
        return;
    } else {
        float* eps = (float*)smem;                    // [32][132]
        float rsv = 0.f;
        if constexpr (EPI == 3) rsv = sigmoidf_(p.resp[p.layer]);

#pragma unroll
        for (int i = 0; i < MT; ++i) {
            __syncthreads();
#pragma unroll
            for (int j = 0; j < NT; ++j) {
                const int colt = wn * 64 + j * 16 + r16;
#pragma unroll
                for (int rr = 0; rr < 4; ++rr) {
                    float v = acc0[i][j][rr];
                    if constexpr (EPI == 1) v *= p.gam[(n0 + colt) >> 1];
                    if constexpr (EPI == 3) v = rsv * v * sigmoidf_(acc1[i][j][rr]);
                    eps[(wm * 16 + q * 4 + rr) * 132 + colt] = v;
                }
            }
            __syncthreads();
            const int row_r = tid >> 3, colg = (tid & 7) * 16;
            const int grow = m0 + (row_r >> 4) * 64 + i * 16 + (row_r & 15);
            const int gcol = n0 + colg;
            float4 f[4];
#pragma unroll
            for (int c = 0; c < 4; ++c) f[c] = *(float4*)&eps[row_r * 132 + colg + c * 4];
            const size_t ob = (size_t)grow * N + gcol;

            if constexpr (EPI == 2) {
                uint_t xp[8];
                *(uint4*)(xp)     = *(const uint4*)(p.xbf_in + ob);
                *(uint4*)(xp + 4) = *(const uint4*)(p.xbf_in + ob + 8);
#pragma unroll
                for (int c = 0; c < 4; ++c) {
                    float4 dv = *(const float4*)(p.Dv + gcol + c * 4);
                    f[c].x += dv.x * bf2f(xp[2 * c]);
                    f[c].y += dv.y * bf2f(xp[2 * c] >> 16);
                    f[c].z += dv.z * bf2f(xp[2 * c + 1]);
                    f[c].w += dv.w * bf2f(xp[2 * c + 1] >> 16);
                }
            } else if constexpr (EPI == 3) {
                uint_t xp[8];
                *(uint4*)(xp)     = *(const uint4*)(p.xbf_in + ob);
                *(uint4*)(xp + 4) = *(const uint4*)(p.xbf_in + ob + 8);
#pragma unroll
                for (int c = 0; c < 4; ++c) {
                    f[c].x += bf2f(xp[2 * c]);
                    f[c].y += bf2f(xp[2 * c] >> 16);
                    f[c].z += bf2f(xp[2 * c + 1]);
                    f[c].w += bf2f(xp[2 * c + 1] >> 16);
                }
            }
            uint4 p0, p1;
            p0.x = pack2(f[0].x, f[0].y); p0.y = pack2(f[0].z, f[0].w);
            p0.z = pack2(f[1].x, f[1].y); p0.w = pack2(f[1].z, f[1].w);
            p1.x = pack2(f[2].x, f[2].y); p1.y = pack2(f[2].z, f[2].w);
            p1.z = pack2(f[3].x, f[3].y); p1.w = pack2(f[3].z, f[3].w);
            *(uint4*)(p.obf + ob) = p0;
            *(uint4*)(p.obf + ob + 8) = p1;
        }
    }
}

// ---------------------------------------------------------------------------
// Single prep kernel: all weight bf16 packing + u cast + lambda/gamma tables.
// ---------------------------------------------------------------------------
__global__ void prep_all(const float* __restrict__ u, const float* __restrict__ enc,
                         const float* __restrict__ dec, const float* __restrict__ nu,
                         const float* __restrict__ th,
                         const float* __restrict__ Bre, const float* __restrict__ Bim,
                         const float* __restrict__ Cre, const float* __restrict__ Cim,
                         const float* __restrict__ W1, const float* __restrict__ W2,
                         ushort_t* __restrict__ WBb, ushort_t* __restrict__ Wzb,
                         ushort_t* __restrict__ W1b, ushort_t* __restrict__ W2b,
                         ushort_t* __restrict__ encb, ushort_t* __restrict__ decb,
                         ushort_t* __restrict__ ubf,
                         float* __restrict__ lre, float* __restrict__ lim,
                         float* __restrict__ gm) {
    const int idx = blockIdx.x * 256 + threadIdx.x;   // 0..1M-1
    const int k = idx & 511, n = (idx >> 9) & 511, l = idx >> 18;
    {
        const int s = n >> 1, part = n & 1;
        const float* src = part ? Bim : Bre;
        WBb[idx] = f2bf(src[((size_t)l * DS + s) * DM + k]);
    }
    {
        const int s = k >> 1, part = k & 1;
        float v = part ? -Cim[((size_t)l * DM + n) * DS + s]
                       :  Cre[((size_t)l * DM + n) * DS + s];
        Wzb[idx] = f2bf(v);
    }
    W1b[idx] = f2bf(W1[idx]);
    W2b[idx] = f2bf(W2[idx]);
    ubf[idx] = f2bf(u[idx]);
    if (idx < DM * 64) { encb[idx] = f2bf(enc[idx]); decb[idx] = f2bf(dec[idx]); }
    if (idx < NL * DS) {
        float a = expf(-expf(nu[idx])), t = expf(th[idx]);
        lre[idx] = a * cosf(t);
        lim[idx] = a * sinf(t);
        gm[idx] = sqrtf(fmaxf(0.f, 1.f - a * a));
    }
}

// ---------------------------------------------------------------------------
// Two-kernel lookback scan — NO inter-block waiting (R2 post-mortem: agent-
// scope spin/fence traffic from 512 blocks cost ~100us; the lookback only
// needs predecessors' LOCAL ends, which kernel 1 fully materializes).
// Kernel 1 (scan_ends, R0-verified): local chunk-end per (b,c) -> carry.
// Kernel 2 (scan_apply_lb): rebuild prefix g from depth-12 truncated
// lookback over carry (|lam^32| <= 0.194 -> 0.194^12 ~ 3e-9 truncation,
// far below bf16 noise; arithmetic verified in R1/R2), then apply + write h.
// Deterministic, no atomics, no fences, one dispatch fewer than R0.
// ---------------------------------------------------------------------------
__global__ __launch_bounds__(256) void scan_ends(
        const uint_t* __restrict__ Bu, const float* __restrict__ lre_,
        const float* __restrict__ lim_, float* __restrict__ carry) {
    const int s = threadIdx.x;
    const int blk = blockIdx.x, b = blk >> 6, c = blk & 63;
    const float lre = lre_[s], lim = lim_[s];
    float hre = 0.f, him = 0.f;
    size_t base = ((size_t)b * SEQ + (size_t)c * LCH) * DS + s;
#pragma unroll 8
    for (int i = 0; i < LCH; ++i, base += DS) {
        uint_t u = Bu[base];
        float br = bf2f(u), bi = bf2f(u >> 16);
        float nr = fmaf(lre, hre, fmaf(-lim, him, br));
        float ni = fmaf(lre, him, fmaf(lim, hre, bi));
        hre = nr; him = ni;
    }
    carry[(size_t)blk * 512 + s] = hre;
    carry[(size_t)blk * 512 + DS + s] = him;
}

__global__ __launch_bounds__(256) void scan_apply_lb(
        const uint_t* __restrict__ Bu, const float* __restrict__ lre_,
        const float* __restrict__ lim_, const float* __restrict__ carry,
        uint_t* __restrict__ h) {
    const int s = threadIdx.x;
    const int blk = blockIdx.x, b = blk >> 6, c = blk & 63;
    const float lre = lre_[s], lim = lim_[s];

    // lookback: g = state at end of chunk c-1 (truncated geometric sum)
    float gre = 0.f, gim = 0.f;
    if (c > 0) {
        float are = lre, aim = lim;          // lam^32 (5 squarings)
#pragma unroll
        for (int t = 0; t < 5; ++t) {
            float nr = are * are - aim * aim, ni = 2.f * are * aim;
            are = nr; aim = ni;
        }
        const int depth = (c < 12) ? c : 12;
        float pwr = 1.f, pwi = 0.f;
        for (int j = c - 1; j >= c - depth; --j) {
            const size_t jb = (size_t)(b * NCH + j) * 512 + s;
            float er = carry[jb], ei = carry[jb + DS];
            gre = fmaf(pwr, er, fmaf(-pwi, ei, gre));
            gim = fmaf(pwr, ei, fmaf(pwi, er, gim));
            float nr = pwr * are - pwi * aim, ni = pwr * aim + pwi * are;
            pwr = nr; pwi = ni;
        }
    }

    // apply: rerun recurrence from g, write h
    float hr = gre, hi = gim;
    size_t base = ((size_t)b * SEQ + (size_t)c * LCH) * DS + s;
#pragma unroll 8
    for (int i = 0; i < LCH; ++i, base += DS) {
        uint_t uu = Bu[base];
        float br = bf2f(uu), bi = bf2f(uu >> 16);
        float nr = fmaf(lre, hr, fmaf(-lim, hi, br));
        float ni = fmaf(lre, hi, fmaf(lim, hr, bi));
        hr = nr; hi = ni;
        h[base] = pack2(hr, hi);
    }
}

// ---------------------------------------------------------------------------
extern "C" void kernel_launch(void* const* d_in, const int* in_sizes, int n_in,
                              void* d_out, int out_size, void* d_ws, size_t ws_size,
                              hipStream_t stream) {
    const float* u   = (const float*)d_in[0];
    const float* enc = (const float*)d_in[1];
    const float* dec = (const float*)d_in[2];
    const float* nu  = (const float*)d_in[3];
    const float* th  = (const float*)d_in[4];
    const float* Bre = (const float*)d_in[5];
    const float* Bim = (const float*)d_in[6];
    const float* Cre = (const float*)d_in[7];
    const float* Cim = (const float*)d_in[8];
    const float* Dp  = (const float*)d_in[9];
    const float* W1  = (const float*)d_in[10];
    const float* W2  = (const float*)d_in[11];
    const float* res = (const float*)d_in[12];
    float* out = (float*)d_out;

    const size_t MD = (size_t)MROWS * DM;
    float* carry = (float*)d_ws;                         // [8*64,512] fp32
    float* lre  = carry + (size_t)BATCH * NCH * 512;
    float* lim  = lre + NL * DS;
    float* gmt  = lim + NL * DS;
    ushort_t* xbf  = (ushort_t*)(gmt + NL * DS);         // bf16 [16384,512] each:
    ushort_t* Bubf = xbf + MD;
    ushort_t* hbf  = Bubf + MD;
    ushort_t* zbf  = hbf + MD;
    ushort_t* ubf  = zbf;                                // alias: z written after u consumed
    ushort_t* WBb  = zbf + MD;                           // weights, 4x512x512 bf16 each:
    ushort_t* Wzb  = WBb + (size_t)NL * DM * DM;
    ushort_t* W1b  = Wzb + (size_t)NL * DM * DM;
    ushort_t* W2b  = W1b + (size_t)NL * DM * DM;
    ushort_t* encb = W2b + (size_t)NL * DM * DM;         // 512x64
    ushort_t* decb = encb + DM * 64;                     // 64x512

    prep_all<<<NL * DM * DM / 256, 256, 0, stream>>>(
        u, enc, dec, nu, th, Bre, Bim, Cre, Cim, W1, W2,
        WBb, Wzb, W1b, W2b, encb, decb, ubf, lre, lim, gmt);

    const dim3 gFull(MROWS / 128, DM / 128);

    // encoder: xbf = bf16(u @ enc^T)
    {
        GemmArgs a = {};
        a.A = ubf; a.Wa = encb; a.K = 64; a.N = DM;
        a.obf = xbf;
        mgemm<128, 0, 0><<<gFull, 256, 0, stream>>>(a);
    }

    for (int k = 0; k < NL; ++k) {
        {   // Bu (interleaved re/im cols, gamma-scaled) -> Bubf
            GemmArgs a = {};
            a.A = xbf; a.Wa = WBb + (size_t)k * DM * DM; a.K = DM; a.N = DM;
            a.obf = Bubf; a.gam = gmt + k * DS;
            mgemm<128, 1, 0><<<gFull, 256, 0, stream>>>(a);
        }
        scan_ends<<<BATCH * NCH, 256, 0, stream>>>((const uint_t*)Bubf,
                                                   lre + k * DS, lim + k * DS, carry);
        scan_apply_lb<<<BATCH * NCH, 256, 0, stream>>>((const uint_t*)Bubf,
                                                       lre + k * DS, lim + k * DS, carry,
                                                       (uint_t*)hbf);
        {   // z = Re(h @ C^T) + D*x  -> zbf
            GemmArgs a = {};
            a.A = hbf; a.Wa = Wzb + (size_t)k * DM * DM; a.K = DM; a.N = DM;
            a.obf = zbf; a.xbf_in = xbf; a.Dv = Dp + k * DM;
            mgemm<128, 2, 0><<<gFull, 256, 0, stream>>>(a);
        }
        {   // xbf += sig(res)*[(z@W1^T)*sigmoid(z@W2^T)]   (bf16 RMW)
            GemmArgs a = {};
            a.A = zbf; a.Wa = W1b + (size_t)k * DM * DM; a.Wb = W2b + (size_t)k * DM * DM;
            a.K = DM; a.N = DM;
            a.obf = xbf; a.xbf_in = xbf; a.resp = res; a.layer = k;
            mgemm<128, 3, 1><<<gFull, 256, 0, stream>>>(a);
        }
    }
    {   // decoder: out = x @ dec^T
        GemmArgs a = {};
        a.A = xbf; a.Wa = decb; a.K = DM; a.N = 64;
        a.of32 = out;
        mgemm<64, 4, 0><<<dim3(MROWS / 128, 1), 256, 0, stream>>>(a);
    }
}

// Round 4
// 369.581 us; speedup vs baseline: 2.1977x; 1.0511x over previous
//
#include <hip/hip_runtime.h>
#include <cmath>

#define DM 512
#define DS 256
#define NL 4
#define BATCH 8
#define SEQ 2048
#define MROWS (BATCH*SEQ)   // 16384
#define LCH 32
#define NCH 64              // LCH*NCH == SEQ

typedef unsigned short ushort_t;
typedef unsigned int uint_t;
typedef __attribute__((ext_vector_type(8))) short short8;
typedef __attribute__((ext_vector_type(4))) float floatx4;

__device__ __forceinline__ float sigmoidf_(float v) { return 1.0f / (1.0f + __expf(-v)); }

__device__ __forceinline__ ushort_t f2bf(float f) {
    union { float f; unsigned int u; } c; c.f = f;
    unsigned int u = c.u;
    u += 0x7fffu + ((u >> 16) & 1u);          // RNE
    return (ushort_t)(u >> 16);
}
__device__ __forceinline__ float bf2f(uint_t h) {
    union { unsigned int u; float f; } c; c.u = (h & 0xffffu) << 16; return c.f;
}
__device__ __forceinline__ uint_t pack2(float a, float b) {
    return (uint_t)f2bf(a) | ((uint_t)f2bf(b) << 16);
}

#define AS1 __attribute__((address_space(1)))
#define AS3 __attribute__((address_space(3)))
__device__ __forceinline__ void gl_lds16(const void* g, void* l) {
    __builtin_amdgcn_global_load_lds((const AS1 uint_t*)g, (AS3 uint_t*)l, 16, 0, 0);
}

// All GEMM arguments in one struct: no positional-arity pitfalls.
struct GemmArgs {
    const ushort_t* A;       // [M,K] bf16
    const ushort_t* Wa;      // [N,K] bf16
    const ushort_t* Wb;      // [N,K] bf16 (DUAL only)
    const ushort_t* xbf_in;  // EPI2/EPI3: bf16 x
    const float* gam;        // EPI1
    const float* Dv;         // EPI2
    float* of32;             // EPI4
    ushort_t* obf;           // EPI0..3
    const float* resp;       // EPI3
    const float* lamre;      // EPI1: lambda tables for fused chunk-end scan
    const float* lamim;      // EPI1
    float* carry;            // EPI1: [B*NCH,512] chunk-end output
    int K;
    int N;
    int layer;
};

// ---------------------------------------------------------------------------
// bf16 MFMA GEMM, double-buffered async global->LDS staging, LDS-transpose
// epilogue. O = A[M,K] @ W[N,K]^T. EPI:
//  0: encoder  -> obf = bf16(acc)
//  1: Bu       -> obf = bf16(acc * gam[col>>1])  (interleaved re/im cols)
//                 + FUSED chunk-end scan: stash packed bf16 tile in LDS,
//                 then 256 threads scan (4 chunks x 64 states) x 32 steps
//                 and write carry directly (replaces scan_ends kernel;
//                 identical numerics: scans the same rounded bf16).
//  2: z        -> obf = bf16(acc + Dv[col]*bf2f(xbf_in[row,col]))
//  3: GLU dual -> obf = bf16(bf2f(xbf_in) + sigmoid(resp[l])*acc0*sigmoid(acc1))
//  4: plain    -> of32 = acc   (decoder, BN=64, direct store)
// launch_bounds 3 (single) / 2 (dual): dual needs >=128 VGPR for acc alone —
// bound 3 forces spills (R13: VGPR 84, +27MB scratch traffic, 28->55us).
// R3 post-mortem: XCD swizzle REVERTED — workload is L3-resident (no HBM
// A-refetch to save) and the swizzle made each XCD's resident blocks span
// all 4 by-panels -> dual GEMM needed 4MB B + 2MB A in a 4MB L2 (thrash),
// +~20us. Natural x-major dispatch keeps same-by blocks co-resident.
// ---------------------------------------------------------------------------
#define PREFETCH_TILE(it_, buf_)                                                        \
    do {                                                                                \
        const size_t kb_ = (size_t)(it_) * 64;                                          \
        char* dst_ = smem + (buf_) * HALF;                                              \
        gl_lds16(Ap + (size_t)(wid * 16 + lrow) * Kb + kb_, dst_ + wid * 1024);         \
        gl_lds16(Ap + (size_t)((wid + 4) * 16 + lrow) * Kb + kb_,                       \
                 dst_ + (wid + 4) * 1024);                                              \
        gl_lds16(B0p + (size_t)(wid * 16 + lrow) * Kb + kb_, dst_ + AB + wid * 1024);   \
        if constexpr (BN == 128) {                                                      \
            gl_lds16(B0p + (size_t)((wid + 4) * 16 + lrow) * Kb + kb_,                  \
                     dst_ + AB + (wid + 4) * 1024);                                     \
        }                                                                               \
        if constexpr (DUAL) {                                                           \
            gl_lds16(B1p + (size_t)(wid * 16 + lrow) * Kb + kb_,                        \
                     dst_ + AB + BB + wid * 1024);                                      \
            if constexpr (BN == 128) {                                                  \
                gl_lds16(B1p + (size_t)((wid + 4) * 16 + lrow) * Kb + kb_,              \
                         dst_ + AB + BB + (wid + 4) * 1024);                            \
            }                                                                           \
        }                                                                               \
    } while (0)

template<int BN, int EPI, int DUAL>
__launch_bounds__(256, DUAL ? 2 : 3)
__global__ void mgemm(const GemmArgs p) {
    constexpr int BM = 128;
    constexpr int MT = (BN == 128) ? 4 : 2;
    constexpr int NT = 4;
    constexpr int WROWS = MT * 16;
    constexpr int AB = 8192;                         // A stage bytes (128 x 64B)
    constexpr int BB = (BN == 128) ? 8192 : 4096;
    constexpr int B1B = DUAL ? BB : 0;
    constexpr int HALF = AB + BB + B1B;              // one pipeline stage
    // EPI1 adds a [128][66]-uint stash (33.8KB) after the [32][132] eps tile.
    constexpr int EPB = (EPI == 4) ? 0
                      : (EPI == 1) ? (32 * 132 * 4 + 128 * 66 * 4)
                      : 32 * 132 * 4;
    constexpr int SMB = (2 * HALF > EPB) ? 2 * HALF : EPB;
    __shared__ __align__(16) char smem[SMB];

    const int K = p.K, N = p.N;
    const int tid = threadIdx.x, lane = tid & 63, wid = tid >> 6;
    const int wm = (BN == 128) ? (wid & 1) : wid;
    const int wn = (BN == 128) ? (wid >> 1) : 0;
    const int m0 = blockIdx.x * BM, n0 = blockIdx.y * BN;
    const int q = lane >> 4, r16 = lane & 15;
    const int lrow = lane >> 2;
    const size_t Kb = (size_t)K * 2;                 // row bytes
    const char* Ap  = (const char*)p.A  + (size_t)m0 * Kb + (lane & 3) * 16;
    const char* B0p = (const char*)p.Wa + (size_t)n0 * Kb + (lane & 3) * 16;
    const char* B1p = (const char*)p.Wb + (size_t)n0 * Kb + (lane & 3) * 16;

    floatx4 acc0[MT][NT] = {};
    floatx4 acc1[DUAL ? MT : 1][DUAL ? NT : 1] = {};

    const int iters = K >> 5;
    PREFETCH_TILE(0, 0);
    for (int it = 0; it < iters; ++it) {
        __syncthreads();
        if (it + 1 < iters) PREFETCH_TILE(it + 1, (it + 1) & 1);
        const ushort_t* As  = (const ushort_t*)(smem + (it & 1) * HALF);
        const ushort_t* Bs0 = (const ushort_t*)(smem + (it & 1) * HALF + AB);
        const ushort_t* Bs1 = (const ushort_t*)(smem + (it & 1) * HALF + AB + BB);

        short8 af[MT], b0[NT], b1[DUAL ? NT : 1];
#pragma unroll
        for (int i = 0; i < MT; ++i)
            af[i] = *(const short8*)&As[(wm * WROWS + i * 16 + r16) * 32 + q * 8];
#pragma unroll
        for (int j = 0; j < NT; ++j) {
            b0[j] = *(const short8*)&Bs0[(wn * 64 + j * 16 + r16) * 32 + q * 8];
            if constexpr (DUAL)
                b1[j] = *(const short8*)&Bs1[(wn * 64 + j * 16 + r16) * 32 + q * 8];
        }
#pragma unroll
        for (int i = 0; i < MT; ++i)
#pragma unroll
            for (int j = 0; j < NT; ++j) {
                acc0[i][j] = __builtin_amdgcn_mfma_f32_16x16x32_bf16(af[i], b0[j], acc0[i][j], 0, 0, 0);
                if constexpr (DUAL)
                    acc1[i][j] = __builtin_amdgcn_mfma_f32_16x16x32_bf16(af[i], b1[j], acc1[i][j], 0, 0, 0);
            }
    }

    if constexpr (EPI == 4) {
#pragma unroll
        for (int i = 0; i < MT; ++i)
#pragma unroll
            for (int j = 0; j < NT; ++j)
#pragma unroll
                for (int rr = 0; rr < 4; ++rr) {
                    const int row = m0 + wm * WROWS + i * 16 + q * 4 + rr;
                    const int col = wn * 64 + j * 16 + r16;
                    p.of32[(size_t)row * N + col] = acc0[i][j][rr];
                }
        return;
    } else {
        float* eps = (float*)smem;                    // [32][132]
        uint_t* zst = (uint_t*)(smem + 32 * 132 * 4); // EPI1: [128][66] packed
        float rsv = 0.f;
        if constexpr (EPI == 3) rsv = sigmoidf_(p.resp[p.layer]);

#pragma unroll
        for (int i = 0; i < MT; ++i) {
            __syncthreads();
#pragma unroll
            for (int j = 0; j < NT; ++j) {
                const int colt = wn * 64 + j * 16 + r16;
#pragma unroll
                for (int rr = 0; rr < 4; ++rr) {
                    float v = acc0[i][j][rr];
                    if constexpr (EPI == 1) v *= p.gam[(n0 + colt) >> 1];
                    if constexpr (EPI == 3) v = rsv * v * sigmoidf_(acc1[i][j][rr]);
                    eps[(wm * 16 + q * 4 + rr) * 132 + colt] = v;
                }
            }
            __syncthreads();
            const int row_r = tid >> 3, colg = (tid & 7) * 16;
            const int lr = (row_r >> 4) * 64 + i * 16 + (row_r & 15);   // local row
            const int grow = m0 + lr;
            const int gcol = n0 + colg;
            float4 f[4];
#pragma unroll
            for (int c = 0; c < 4; ++c) f[c] = *(float4*)&eps[row_r * 132 + colg + c * 4];
            const size_t ob = (size_t)grow * N + gcol;

            if constexpr (EPI == 2) {
                uint_t xp[8];
                *(uint4*)(xp)     = *(const uint4*)(p.xbf_in + ob);
                *(uint4*)(xp + 4) = *(const uint4*)(p.xbf_in + ob + 8);
#pragma unroll
                for (int c = 0; c < 4; ++c) {
                    float4 dv = *(const float4*)(p.Dv + gcol + c * 4);
                    f[c].x += dv.x * bf2f(xp[2 * c]);
                    f[c].y += dv.y * bf2f(xp[2 * c] >> 16);
                    f[c].z += dv.z * bf2f(xp[2 * c + 1]);
                    f[c].w += dv.w * bf2f(xp[2 * c + 1] >> 16);
                }
            } else if constexpr (EPI == 3) {
                uint_t xp[8];
                *(uint4*)(xp)     = *(const uint4*)(p.xbf_in + ob);
                *(uint4*)(xp + 4) = *(const uint4*)(p.xbf_in + ob + 8);
#pragma unroll
                for (int c = 0; c < 4; ++c) {
                    f[c].x += bf2f(xp[2 * c]);
                    f[c].y += bf2f(xp[2 * c] >> 16);
                    f[c].z += bf2f(xp[2 * c + 1]);
                    f[c].w += bf2f(xp[2 * c + 1] >> 16);
                }
            }
            uint4 p0, p1;
            p0.x = pack2(f[0].x, f[0].y); p0.y = pack2(f[0].z, f[0].w);
            p0.z = pack2(f[1].x, f[1].y); p0.w = pack2(f[1].z, f[1].w);
            p1.x = pack2(f[2].x, f[2].y); p1.y = pack2(f[2].z, f[2].w);
            p1.z = pack2(f[3].x, f[3].y); p1.w = pack2(f[3].z, f[3].w);
            *(uint4*)(p.obf + ob) = p0;
            *(uint4*)(p.obf + ob + 8) = p1;
            if constexpr (EPI == 1) {
                // stash packed (re,im) pairs: local row lr, local states colg/2..+7
                const int c0 = colg >> 1;
                *(uint4*)&zst[lr * 66 + c0]     = p0;
                *(uint4*)&zst[lr * 66 + c0 + 4] = p1;
            }
        }

        if constexpr (EPI == 1) {
            // fused chunk-end scan: thread t -> chunk c4 (of 4), local state s6
            __syncthreads();
            const int c4 = tid >> 6, s6 = tid & 63;
            const int sg = (n0 >> 1) + s6;                 // global state
            const float lr_ = p.lamre[sg], li_ = p.lamim[sg];
            float hr = 0.f, hi = 0.f;
#pragma unroll 8
            for (int i2 = 0; i2 < LCH; ++i2) {
                uint_t uu = zst[(c4 * LCH + i2) * 66 + s6];
                float br = bf2f(uu), bi = bf2f(uu >> 16);
                float nr = fmaf(lr_, hr, fmaf(-li_, hi, br));
                float ni = fmaf(lr_, hi, fmaf(li_, hr, bi));
                hr = nr; hi = ni;
            }
            const int b = m0 >> 11;                        // m0 / SEQ
            const int cblk = ((m0 & (SEQ - 1)) >> 5) + c4; // chunk index in seq
            const size_t cb = (size_t)(b * NCH + cblk) * 512 + sg;
            p.carry[cb] = hr; p.carry[cb + DS] = hi;
        }
    }
}

// ---------------------------------------------------------------------------
// Single prep kernel: all weight bf16 packing + u cast + lambda/gamma tables.
// ---------------------------------------------------------------------------
__global__ void prep_all(const float* __restrict__ u, const float* __restrict__ enc,
                         const float* __restrict__ dec, const float* __restrict__ nu,
                         const float* __restrict__ th,
                         const float* __restrict__ Bre, const float* __restrict__ Bim,
                         const float* __restrict__ Cre, const float* __restrict__ Cim,
                         const float* __restrict__ W1, const float* __restrict__ W2,
                         ushort_t* __restrict__ WBb, ushort_t* __restrict__ Wzb,
                         ushort_t* __restrict__ W1b, ushort_t* __restrict__ W2b,
                         ushort_t* __restrict__ encb, ushort_t* __restrict__ decb,
                         ushort_t* __restrict__ ubf,
                         float* __restrict__ lre, float* __restrict__ lim,
                         float* __restrict__ gm) {
    const int idx = blockIdx.x * 256 + threadIdx.x;   // 0..1M-1
    const int k = idx & 511, n = (idx >> 9) & 511, l = idx >> 18;
    {
        const int s = n >> 1, part = n & 1;
        const float* src = part ? Bim : Bre;
        WBb[idx] = f2bf(src[((size_t)l * DS + s) * DM + k]);
    }
    {
        const int s = k >> 1, part = k & 1;
        float v = part ? -Cim[((size_t)l * DM + n) * DS + s]
                       :  Cre[((size_t)l * DM + n) * DS + s];
        Wzb[idx] = f2bf(v);
    }
    W1b[idx] = f2bf(W1[idx]);
    W2b[idx] = f2bf(W2[idx]);
    ubf[idx] = f2bf(u[idx]);
    if (idx < DM * 64) { encb[idx] = f2bf(enc[idx]); decb[idx] = f2bf(dec[idx]); }
    if (idx < NL * DS) {
        float a = expf(-expf(nu[idx])), t = expf(th[idx]);
        lre[idx] = a * cosf(t);
        lim[idx] = a * sinf(t);
        gm[idx] = sqrtf(fmaxf(0.f, 1.f - a * a));
    }
}

// ---------------------------------------------------------------------------
// Lookback apply — NO inter-block waiting (R2 post-mortem: agent-scope spin
// cost ~100us). Chunk-end carries are produced by the Bu-GEMM epilogue
// (fused scan_ends). This kernel rebuilds prefix g from a depth-12 truncated
// lookback over carry (|lam^32| <= 0.194 -> 0.194^12 ~ 3e-9 truncation, far
// below bf16 noise; arithmetic verified R1-R3), then applies + writes h.
// Deterministic, no atomics, no fences.
// ---------------------------------------------------------------------------
__global__ __launch_bounds__(256) void scan_apply_lb(
        const uint_t* __restrict__ Bu, const float* __restrict__ lre_,
        const float* __restrict__ lim_, const float* __restrict__ carry,
        uint_t* __restrict__ h) {
    const int s = threadIdx.x;
    const int blk = blockIdx.x, b = blk >> 6, c = blk & 63;
    const float lre = lre_[s], lim = lim_[s];

    // lookback: g = state at end of chunk c-1 (truncated geometric sum)
    float gre = 0.f, gim = 0.f;
    if (c > 0) {
        float are = lre, aim = lim;          // lam^32 (5 squarings)
#pragma unroll
        for (int t = 0; t < 5; ++t) {
            float nr = are * are - aim * aim, ni = 2.f * are * aim;
            are = nr; aim = ni;
        }
        const int depth = (c < 12) ? c : 12;
        float pwr = 1.f, pwi = 0.f;
        for (int j = c - 1; j >= c - depth; --j) {
            const size_t jb = (size_t)(b * NCH + j) * 512 + s;
            float er = carry[jb], ei = carry[jb + DS];
            gre = fmaf(pwr, er, fmaf(-pwi, ei, gre));
            gim = fmaf(pwr, ei, fmaf(pwi, er, gim));
            float nr = pwr * are - pwi * aim, ni = pwr * aim + pwi * are;
            pwr = nr; pwi = ni;
        }
    }

    // apply: rerun recurrence from g, write h
    float hr = gre, hi = gim;
    size_t base = ((size_t)b * SEQ + (size_t)c * LCH) * DS + s;
#pragma unroll 8
    for (int i = 0; i < LCH; ++i, base += DS) {
        uint_t uu = Bu[base];
        float br = bf2f(uu), bi = bf2f(uu >> 16);
        float nr = fmaf(lre, hr, fmaf(-lim, hi, br));
        float ni = fmaf(lre, hi, fmaf(lim, hr, bi));
        hr = nr; hi = ni;
        h[base] = pack2(hr, hi);
    }
}

// ---------------------------------------------------------------------------
extern "C" void kernel_launch(void* const* d_in, const int* in_sizes, int n_in,
                              void* d_out, int out_size, void* d_ws, size_t ws_size,
                              hipStream_t stream) {
    const float* u   = (const float*)d_in[0];
    const float* enc = (const float*)d_in[1];
    const float* dec = (const float*)d_in[2];
    const float* nu  = (const float*)d_in[3];
    const float* th  = (const float*)d_in[4];
    const float* Bre = (const float*)d_in[5];
    const float* Bim = (const float*)d_in[6];
    const float* Cre = (const float*)d_in[7];
    const float* Cim = (const float*)d_in[8];
    const float* Dp  = (const float*)d_in[9];
    const float* W1  = (const float*)d_in[10];
    const float* W2  = (const float*)d_in[11];
    const float* res = (const float*)d_in[12];
    float* out = (float*)d_out;

    const size_t MD = (size_t)MROWS * DM;
    float* carry = (float*)d_ws;                         // [8*64,512] fp32
    float* lre  = carry + (size_t)BATCH * NCH * 512;
    float* lim  = lre + NL * DS;
    float* gmt  = lim + NL * DS;
    ushort_t* xbf  = (ushort_t*)(gmt + NL * DS);         // bf16 [16384,512] each:
    ushort_t* Bubf = xbf + MD;
    ushort_t* hbf  = Bubf + MD;
    ushort_t* zbf  = hbf + MD;
    ushort_t* ubf  = zbf;                                // alias: z written after u consumed
    ushort_t* WBb  = zbf + MD;                           // weights, 4x512x512 bf16 each:
    ushort_t* Wzb  = WBb + (size_t)NL * DM * DM;
    ushort_t* W1b  = Wzb + (size_t)NL * DM * DM;
    ushort_t* W2b  = W1b + (size_t)NL * DM * DM;
    ushort_t* encb = W2b + (size_t)NL * DM * DM;         // 512x64
    ushort_t* decb = encb + DM * 64;                     // 64x512

    prep_all<<<NL * DM * DM / 256, 256, 0, stream>>>(
        u, enc, dec, nu, th, Bre, Bim, Cre, Cim, W1, W2,
        WBb, Wzb, W1b, W2b, encb, decb, ubf, lre, lim, gmt);

    const dim3 gFull(MROWS / 128, DM / 128);

    // encoder: xbf = bf16(u @ enc^T)
    {
        GemmArgs a = {};
        a.A = ubf; a.Wa = encb; a.K = 64; a.N = DM;
        a.obf = xbf;
        mgemm<128, 0, 0><<<gFull, 256, 0, stream>>>(a);
    }

    for (int k = 0; k < NL; ++k) {
        {   // Bu (interleaved re/im cols, gamma-scaled) -> Bubf, + fused chunk-ends
            GemmArgs a = {};
            a.A = xbf; a.Wa = WBb + (size_t)k * DM * DM; a.K = DM; a.N = DM;
            a.obf = Bubf; a.gam = gmt + k * DS;
            a.lamre = lre + k * DS; a.lamim = lim + k * DS; a.carry = carry;
            mgemm<128, 1, 0><<<gFull, 256, 0, stream>>>(a);
        }
        scan_apply_lb<<<BATCH * NCH, 256, 0, stream>>>((const uint_t*)Bubf,
                                                       lre + k * DS, lim + k * DS, carry,
                                                       (uint_t*)hbf);
        {   // z = Re(h @ C^T) + D*x  -> zbf
            GemmArgs a = {};
            a.A = hbf; a.Wa = Wzb + (size_t)k * DM * DM; a.K = DM; a.N = DM;
            a.obf = zbf; a.xbf_in = xbf; a.Dv = Dp + k * DM;
            mgemm<128, 2, 0><<<gFull, 256, 0, stream>>>(a);
        }
        {   // xbf += sig(res)*[(z@W1^T)*sigmoid(z@W2^T)]   (bf16 RMW)
            GemmArgs a = {};
            a.A = zbf; a.Wa = W1b + (size_t)k * DM * DM; a.Wb = W2b + (size_t)k * DM * DM;
            a.K = DM; a.N = DM;
            a.obf = xbf; a.xbf_in = xbf; a.resp = res; a.layer = k;
            mgemm<128, 3, 1><<<gFull, 256, 0, stream>>>(a);
        }
    }
    {   // decoder: out = x @ dec^T
        GemmArgs a = {};
        a.A = xbf; a.Wa = decb; a.K = DM; a.N = 64;
        a.of32 = out;
        mgemm<64, 4, 0><<<dim3(MROWS / 128, 1), 256, 0, stream>>>(a);
    }
}

// Round 5
// 359.601 us; speedup vs baseline: 2.2587x; 1.0278x over previous
//
#include <hip/hip_runtime.h>
#include <cmath>

#define DM 512
#define DS 256
#define NL 4
#define BATCH 8
#define SEQ 2048
#define MROWS (BATCH*SEQ)   // 16384
#define LCH 32
#define NCH 64              // LCH*NCH == SEQ

typedef unsigned short ushort_t;
typedef unsigned int uint_t;
typedef __attribute__((ext_vector_type(8))) short short8;
typedef __attribute__((ext_vector_type(4))) float floatx4;

__device__ __forceinline__ float sigmoidf_(float v) { return 1.0f / (1.0f + __expf(-v)); }

__device__ __forceinline__ ushort_t f2bf(float f) {
    union { float f; unsigned int u; } c; c.f = f;
    unsigned int u = c.u;
    u += 0x7fffu + ((u >> 16) & 1u);          // RNE
    return (ushort_t)(u >> 16);
}
__device__ __forceinline__ float bf2f(uint_t h) {
    union { unsigned int u; float f; } c; c.u = (h & 0xffffu) << 16; return c.f;
}
__device__ __forceinline__ uint_t pack2(float a, float b) {
    return (uint_t)f2bf(a) | ((uint_t)f2bf(b) << 16);
}

#define AS1 __attribute__((address_space(1)))
#define AS3 __attribute__((address_space(3)))
__device__ __forceinline__ void gl_lds16(const void* g, void* l) {
    __builtin_amdgcn_global_load_lds((const AS1 uint_t*)g, (AS3 uint_t*)l, 16, 0, 0);
}

// All GEMM arguments in one struct: no positional-arity pitfalls.
struct GemmArgs {
    const ushort_t* A;       // [M,K] bf16
    const ushort_t* Wa;      // [N,K] bf16
    const ushort_t* Wb;      // [N,K] bf16 (DUAL only)
    const ushort_t* xbf_in;  // EPI2/EPI3: bf16 x
    const float* gam;        // EPI1
    const float* Dv;         // EPI2
    float* of32;             // EPI4
    ushort_t* obf;           // EPI0..3
    const float* resp;       // EPI3
    const float* lamre;      // EPI1: lambda tables for fused chunk-end scan
    const float* lamim;      // EPI1
    float* carry;            // EPI1: [B*NCH,512] chunk-end output
    int K;
    int N;
    int layer;
};

// ---------------------------------------------------------------------------
// bf16 MFMA GEMM, double-buffered async global->LDS staging, LDS-transpose
// epilogue. O = A[M,K] @ W[N,K]^T. EPI:
//  0: encoder  -> obf = bf16(acc)
//  1: Bu       -> obf = bf16(acc * gam[col>>1])  (interleaved re/im cols)
//                 + FUSED chunk-end scan: stash packed bf16 tile in LDS,
//                 then 256 threads scan (4 chunks x 64 states) x 32 steps
//                 and write carry directly (replaces scan_ends kernel;
//                 identical numerics: scans the same rounded bf16).
//  2: z        -> obf = bf16(acc + Dv[col]*bf2f(xbf_in[row,col]))
//  3: GLU dual -> obf = bf16(bf2f(xbf_in) + sigmoid(resp[l])*acc0*sigmoid(acc1))
//  4: plain    -> of32 = acc   (decoder, BN=64, direct store)
// launch_bounds 3 (single) / 2 (dual): dual needs >=128 VGPR for acc alone —
// bound 3 forces spills (R13: VGPR 84, +27MB scratch traffic, 28->55us).
// R3 post-mortem: XCD swizzle REVERTED — workload is L3-resident (no HBM
// A-refetch to save) and the swizzle made each XCD's resident blocks span
// all 4 by-panels -> dual GEMM needed 4MB B + 2MB A in a 4MB L2 (thrash),
// +~20us. Natural x-major dispatch keeps same-by blocks co-resident
// (blocks bx, bx+128, bx+256, bx+384 share A-rows AND the same XCD).
// R4->R5: epilogue rounds halved (ERND=2, eps [64][132]) for EPI0/2/3 —
// 4 of 8 epilogue barriers+drains removed per GEMM, 2x store MLP/round.
// EPI1 keeps 32-row rounds (zst stash + occupancy-3 constraint: 50.6KB*3
// fits 160KB; 64-row eps would force occupancy 2).
// ---------------------------------------------------------------------------
#define PREFETCH_TILE(it_, buf_)                                                        \
    do {                                                                                \
        const size_t kb_ = (size_t)(it_) * 64;                                          \
        char* dst_ = smem + (buf_) * HALF;                                              \
        gl_lds16(Ap + (size_t)(wid * 16 + lrow) * Kb + kb_, dst_ + wid * 1024);         \
        gl_lds16(Ap + (size_t)((wid + 4) * 16 + lrow) * Kb + kb_,                       \
                 dst_ + (wid + 4) * 1024);                                              \
        gl_lds16(B0p + (size_t)(wid * 16 + lrow) * Kb + kb_, dst_ + AB + wid * 1024);   \
        if constexpr (BN == 128) {                                                      \
            gl_lds16(B0p + (size_t)((wid + 4) * 16 + lrow) * Kb + kb_,                  \
                     dst_ + AB + (wid + 4) * 1024);                                     \
        }                                                                               \
        if constexpr (DUAL) {                                                           \
            gl_lds16(B1p + (size_t)(wid * 16 + lrow) * Kb + kb_,                        \
                     dst_ + AB + BB + wid * 1024);                                      \
            if constexpr (BN == 128) {                                                  \
                gl_lds16(B1p + (size_t)((wid + 4) * 16 + lrow) * Kb + kb_,              \
                         dst_ + AB + BB + (wid + 4) * 1024);                            \
            }                                                                           \
        }                                                                               \
    } while (0)

template<int BN, int EPI, int DUAL>
__launch_bounds__(256, DUAL ? 2 : 3)
__global__ void mgemm(const GemmArgs p) {
    constexpr int BM = 128;
    constexpr int MT = (BN == 128) ? 4 : 2;
    constexpr int NT = 4;
    constexpr int WROWS = MT * 16;
    constexpr int AB = 8192;                         // A stage bytes (128 x 64B)
    constexpr int BB = (BN == 128) ? 8192 : 4096;
    constexpr int B1B = DUAL ? BB : 0;
    constexpr int HALF = AB + BB + B1B;              // one pipeline stage
    // epilogue LDS: EPI1 = [32][132] eps + [128][66] zst; EPI0/2/3 = [64][132]
    constexpr int EPB = (EPI == 4) ? 0
                      : (EPI == 1) ? (32 * 132 * 4 + 128 * 66 * 4)
                      : 64 * 132 * 4;
    constexpr int SMB = (2 * HALF > EPB) ? 2 * HALF : EPB;
    __shared__ __align__(16) char smem[SMB];

    const int K = p.K, N = p.N;
    const int tid = threadIdx.x, lane = tid & 63, wid = tid >> 6;
    const int wm = (BN == 128) ? (wid & 1) : wid;
    const int wn = (BN == 128) ? (wid >> 1) : 0;
    const int m0 = blockIdx.x * BM, n0 = blockIdx.y * BN;
    const int q = lane >> 4, r16 = lane & 15;
    const int lrow = lane >> 2;
    const size_t Kb = (size_t)K * 2;                 // row bytes
    const char* Ap  = (const char*)p.A  + (size_t)m0 * Kb + (lane & 3) * 16;
    const char* B0p = (const char*)p.Wa + (size_t)n0 * Kb + (lane & 3) * 16;
    const char* B1p = (const char*)p.Wb + (size_t)n0 * Kb + (lane & 3) * 16;

    floatx4 acc0[MT][NT] = {};
    floatx4 acc1[DUAL ? MT : 1][DUAL ? NT : 1] = {};

    const int iters = K >> 5;
    PREFETCH_TILE(0, 0);
    for (int it = 0; it < iters; ++it) {
        __syncthreads();
        if (it + 1 < iters) PREFETCH_TILE(it + 1, (it + 1) & 1);
        const ushort_t* As  = (const ushort_t*)(smem + (it & 1) * HALF);
        const ushort_t* Bs0 = (const ushort_t*)(smem + (it & 1) * HALF + AB);
        const ushort_t* Bs1 = (const ushort_t*)(smem + (it & 1) * HALF + AB + BB);

        short8 af[MT], b0[NT], b1[DUAL ? NT : 1];
#pragma unroll
        for (int i = 0; i < MT; ++i)
            af[i] = *(const short8*)&As[(wm * WROWS + i * 16 + r16) * 32 + q * 8];
#pragma unroll
        for (int j = 0; j < NT; ++j) {
            b0[j] = *(const short8*)&Bs0[(wn * 64 + j * 16 + r16) * 32 + q * 8];
            if constexpr (DUAL)
                b1[j] = *(const short8*)&Bs1[(wn * 64 + j * 16 + r16) * 32 + q * 8];
        }
#pragma unroll
        for (int i = 0; i < MT; ++i)
#pragma unroll
            for (int j = 0; j < NT; ++j) {
                acc0[i][j] = __builtin_amdgcn_mfma_f32_16x16x32_bf16(af[i], b0[j], acc0[i][j], 0, 0, 0);
                if constexpr (DUAL)
                    acc1[i][j] = __builtin_amdgcn_mfma_f32_16x16x32_bf16(af[i], b1[j], acc1[i][j], 0, 0, 0);
            }
    }

    if constexpr (EPI == 4) {
#pragma unroll
        for (int i = 0; i < MT; ++i)
#pragma unroll
            for (int j = 0; j < NT; ++j)
#pragma unroll
                for (int rr = 0; rr < 4; ++rr) {
                    const int row = m0 + wm * WROWS + i * 16 + q * 4 + rr;
                    const int col = wn * 64 + j * 16 + r16;
                    p.of32[(size_t)row * N + col] = acc0[i][j][rr];
                }
        return;
    } else {
        float* eps = (float*)smem;                    // [ERND*32][132]
        uint_t* zst = (uint_t*)(smem + 32 * 132 * 4); // EPI1 only: [128][66]
        float rsv = 0.f;
        if constexpr (EPI == 3) rsv = sigmoidf_(p.resp[p.layer]);
        constexpr int ERND = (EPI == 1) ? 1 : 2;      // acc i-slabs per eps round

#pragma unroll
        for (int i = 0; i < MT; i += ERND) {
            __syncthreads();
#pragma unroll
            for (int ii = 0; ii < ERND; ++ii) {
#pragma unroll
                for (int j = 0; j < NT; ++j) {
                    const int colt = wn * 64 + j * 16 + r16;
#pragma unroll
                    for (int rr = 0; rr < 4; ++rr) {
                        float v = acc0[i + ii][j][rr];
                        if constexpr (EPI == 1) v *= p.gam[(n0 + colt) >> 1];
                        if constexpr (EPI == 3) v = rsv * v * sigmoidf_(acc1[i + ii][j][rr]);
                        eps[(ii * 32 + wm * 16 + q * 4 + rr) * 132 + colt] = v;
                    }
                }
            }
            __syncthreads();
            const int row_r = tid >> 3, colg = (tid & 7) * 16;
#pragma unroll
            for (int ii = 0; ii < ERND; ++ii) {
                const int lr = (row_r >> 4) * 64 + (i + ii) * 16 + (row_r & 15);  // local row
                const int grow = m0 + lr;
                const int gcol = n0 + colg;
                float4 f[4];
#pragma unroll
                for (int c = 0; c < 4; ++c)
                    f[c] = *(float4*)&eps[(ii * 32 + row_r) * 132 + colg + c * 4];
                const size_t ob = (size_t)grow * N + gcol;

                if constexpr (EPI == 2) {
                    uint_t xp[8];
                    *(uint4*)(xp)     = *(const uint4*)(p.xbf_in + ob);
                    *(uint4*)(xp + 4) = *(const uint4*)(p.xbf_in + ob + 8);
#pragma unroll
                    for (int c = 0; c < 4; ++c) {
                        float4 dv = *(const float4*)(p.Dv + gcol + c * 4);
                        f[c].x += dv.x * bf2f(xp[2 * c]);
                        f[c].y += dv.y * bf2f(xp[2 * c] >> 16);
                        f[c].z += dv.z * bf2f(xp[2 * c + 1]);
                        f[c].w += dv.w * bf2f(xp[2 * c + 1] >> 16);
                    }
                } else if constexpr (EPI == 3) {
                    uint_t xp[8];
                    *(uint4*)(xp)     = *(const uint4*)(p.xbf_in + ob);
                    *(uint4*)(xp + 4) = *(const uint4*)(p.xbf_in + ob + 8);
#pragma unroll
                    for (int c = 0; c < 4; ++c) {
                        f[c].x += bf2f(xp[2 * c]);
                        f[c].y += bf2f(xp[2 * c] >> 16);
                        f[c].z += bf2f(xp[2 * c + 1]);
                        f[c].w += bf2f(xp[2 * c + 1] >> 16);
                    }
                }
                uint4 p0, p1;
                p0.x = pack2(f[0].x, f[0].y); p0.y = pack2(f[0].z, f[0].w);
                p0.z = pack2(f[1].x, f[1].y); p0.w = pack2(f[1].z, f[1].w);
                p1.x = pack2(f[2].x, f[2].y); p1.y = pack2(f[2].z, f[2].w);
                p1.z = pack2(f[3].x, f[3].y); p1.w = pack2(f[3].z, f[3].w);
                *(uint4*)(p.obf + ob) = p0;
                *(uint4*)(p.obf + ob + 8) = p1;
                if constexpr (EPI == 1) {
                    // stash packed (re,im) pairs: local row lr, local states colg/2..+7
                    const int c0 = colg >> 1;
                    *(uint4*)&zst[lr * 66 + c0]     = p0;
                    *(uint4*)&zst[lr * 66 + c0 + 4] = p1;
                }
            }
        }

        if constexpr (EPI == 1) {
            // fused chunk-end scan: thread t -> chunk c4 (of 4), local state s6
            __syncthreads();
            const int c4 = tid >> 6, s6 = tid & 63;
            const int sg = (n0 >> 1) + s6;                 // global state
            const float lr_ = p.lamre[sg], li_ = p.lamim[sg];
            float hr = 0.f, hi = 0.f;
#pragma unroll 8
            for (int i2 = 0; i2 < LCH; ++i2) {
                uint_t uu = zst[(c4 * LCH + i2) * 66 + s6];
                float br = bf2f(uu), bi = bf2f(uu >> 16);
                float nr = fmaf(lr_, hr, fmaf(-li_, hi, br));
                float ni = fmaf(lr_, hi, fmaf(li_, hr, bi));
                hr = nr; hi = ni;
            }
            const int b = m0 >> 11;                        // m0 / SEQ
            const int cblk = ((m0 & (SEQ - 1)) >> 5) + c4; // chunk index in seq
            const size_t cb = (size_t)(b * NCH + cblk) * 512 + sg;
            p.carry[cb] = hr; p.carry[cb + DS] = hi;
        }
    }
}

// ---------------------------------------------------------------------------
// Single prep kernel: all weight bf16 packing + u cast + lambda/gamma tables.
// ---------------------------------------------------------------------------
__global__ void prep_all(const float* __restrict__ u, const float* __restrict__ enc,
                         const float* __restrict__ dec, const float* __restrict__ nu,
                         const float* __restrict__ th,
                         const float* __restrict__ Bre, const float* __restrict__ Bim,
                         const float* __restrict__ Cre, const float* __restrict__ Cim,
                         const float* __restrict__ W1, const float* __restrict__ W2,
                         ushort_t* __restrict__ WBb, ushort_t* __restrict__ Wzb,
                         ushort_t* __restrict__ W1b, ushort_t* __restrict__ W2b,
                         ushort_t* __restrict__ encb, ushort_t* __restrict__ decb,
                         ushort_t* __restrict__ ubf,
                         float* __restrict__ lre, float* __restrict__ lim,
                         float* __restrict__ gm) {
    const int idx = blockIdx.x * 256 + threadIdx.x;   // 0..1M-1
    const int k = idx & 511, n = (idx >> 9) & 511, l = idx >> 18;
    {
        const int s = n >> 1, part = n & 1;
        const float* src = part ? Bim : Bre;
        WBb[idx] = f2bf(src[((size_t)l * DS + s) * DM + k]);
    }
    {
        const int s = k >> 1, part = k & 1;
        float v = part ? -Cim[((size_t)l * DM + n) * DS + s]
                       :  Cre[((size_t)l * DM + n) * DS + s];
        Wzb[idx] = f2bf(v);
    }
    W1b[idx] = f2bf(W1[idx]);
    W2b[idx] = f2bf(W2[idx]);
    ubf[idx] = f2bf(u[idx]);
    if (idx < DM * 64) { encb[idx] = f2bf(enc[idx]); decb[idx] = f2bf(dec[idx]); }
    if (idx < NL * DS) {
        float a = expf(-expf(nu[idx])), t = expf(th[idx]);
        lre[idx] = a * cosf(t);
        lim[idx] = a * sinf(t);
        gm[idx] = sqrtf(fmaxf(0.f, 1.f - a * a));
    }
}

// ---------------------------------------------------------------------------
// Lookback apply — NO inter-block waiting (R2 post-mortem: agent-scope spin
// cost ~100us). Chunk-end carries are produced by the Bu-GEMM epilogue
// (fused scan_ends). This kernel rebuilds prefix g from a depth-12 truncated
// lookback over carry (|lam^32| <= 0.194 -> 0.194^12 ~ 3e-9 truncation, far
// below bf16 noise; arithmetic verified R1-R4), then applies + writes h.
// Deterministic, no atomics, no fences.
// ---------------------------------------------------------------------------
__global__ __launch_bounds__(256) void scan_apply_lb(
        const uint_t* __restrict__ Bu, const float* __restrict__ lre_,
        const float* __restrict__ lim_, const float* __restrict__ carry,
        uint_t* __restrict__ h) {
    const int s = threadIdx.x;
    const int blk = blockIdx.x, b = blk >> 6, c = blk & 63;
    const float lre = lre_[s], lim = lim_[s];

    // lookback: g = state at end of chunk c-1 (truncated geometric sum)
    float gre = 0.f, gim = 0.f;
    if (c > 0) {
        float are = lre, aim = lim;          // lam^32 (5 squarings)
#pragma unroll
        for (int t = 0; t < 5; ++t) {
            float nr = are * are - aim * aim, ni = 2.f * are * aim;
            are = nr; aim = ni;
        }
        const int depth = (c < 12) ? c : 12;
        float pwr = 1.f, pwi = 0.f;
        for (int j = c - 1; j >= c - depth; --j) {
            const size_t jb = (size_t)(b * NCH + j) * 512 + s;
            float er = carry[jb], ei = carry[jb + DS];
            gre = fmaf(pwr, er, fmaf(-pwi, ei, gre));
            gim = fmaf(pwr, ei, fmaf(pwi, er, gim));
            float nr = pwr * are - pwi * aim, ni = pwr * aim + pwi * are;
            pwr = nr; pwi = ni;
        }
    }

    // apply: rerun recurrence from g, write h
    float hr = gre, hi = gim;
    size_t base = ((size_t)b * SEQ + (size_t)c * LCH) * DS + s;
#pragma unroll 8
    for (int i = 0; i < LCH; ++i, base += DS) {
        uint_t uu = Bu[base];
        float br = bf2f(uu), bi = bf2f(uu >> 16);
        float nr = fmaf(lre, hr, fmaf(-lim, hi, br));
        float ni = fmaf(lre, hi, fmaf(lim, hr, bi));
        hr = nr; hi = ni;
        h[base] = pack2(hr, hi);
    }
}

// ---------------------------------------------------------------------------
extern "C" void kernel_launch(void* const* d_in, const int* in_sizes, int n_in,
                              void* d_out, int out_size, void* d_ws, size_t ws_size,
                              hipStream_t stream) {
    const float* u   = (const float*)d_in[0];
    const float* enc = (const float*)d_in[1];
    const float* dec = (const float*)d_in[2];
    const float* nu  = (const float*)d_in[3];
    const float* th  = (const float*)d_in[4];
    const float* Bre = (const float*)d_in[5];
    const float* Bim = (const float*)d_in[6];
    const float* Cre = (const float*)d_in[7];
    const float* Cim = (const float*)d_in[8];
    const float* Dp  = (const float*)d_in[9];
    const float* W1  = (const float*)d_in[10];
    const float* W2  = (const float*)d_in[11];
    const float* res = (const float*)d_in[12];
    float* out = (float*)d_out;

    const size_t MD = (size_t)MROWS * DM;
    float* carry = (float*)d_ws;                         // [8*64,512] fp32
    float* lre  = carry + (size_t)BATCH * NCH * 512;
    float* lim  = lre + NL * DS;
    float* gmt  = lim + NL * DS;
    ushort_t* xbf  = (ushort_t*)(gmt + NL * DS);         // bf16 [16384,512] each:
    ushort_t* Bubf = xbf + MD;
    ushort_t* hbf  = Bubf + MD;
    ushort_t* zbf  = hbf + MD;
    ushort_t* ubf  = zbf;                                // alias: z written after u consumed
    ushort_t* WBb  = zbf + MD;                           // weights, 4x512x512 bf16 each:
    ushort_t* Wzb  = WBb + (size_t)NL * DM * DM;
    ushort_t* W1b  = Wzb + (size_t)NL * DM * DM;
    ushort_t* W2b  = W1b + (size_t)NL * DM * DM;
    ushort_t* encb = W2b + (size_t)NL * DM * DM;         // 512x64
    ushort_t* decb = encb + DM * 64;                     // 64x512

    prep_all<<<NL * DM * DM / 256, 256, 0, stream>>>(
        u, enc, dec, nu, th, Bre, Bim, Cre, Cim, W1, W2,
        WBb, Wzb, W1b, W2b, encb, decb, ubf, lre, lim, gmt);

    const dim3 gFull(MROWS / 128, DM / 128);

    // encoder: xbf = bf16(u @ enc^T)
    {
        GemmArgs a = {};
        a.A = ubf; a.Wa = encb; a.K = 64; a.N = DM;
        a.obf = xbf;
        mgemm<128, 0, 0><<<gFull, 256, 0, stream>>>(a);
    }

    for (int k = 0; k < NL; ++k) {
        {   // Bu (interleaved re/im cols, gamma-scaled) -> Bubf, + fused chunk-ends
            GemmArgs a = {};
            a.A = xbf; a.Wa = WBb + (size_t)k * DM * DM; a.K = DM; a.N = DM;
            a.obf = Bubf; a.gam = gmt + k * DS;
            a.lamre = lre + k * DS; a.lamim = lim + k * DS; a.carry = carry;
            mgemm<128, 1, 0><<<gFull, 256, 0, stream>>>(a);
        }
        scan_apply_lb<<<BATCH * NCH, 256, 0, stream>>>((const uint_t*)Bubf,
                                                       lre + k * DS, lim + k * DS, carry,
                                                       (uint_t*)hbf);
        {   // z = Re(h @ C^T) + D*x  -> zbf
            GemmArgs a = {};
            a.A = hbf; a.Wa = Wzb + (size_t)k * DM * DM; a.K = DM; a.N = DM;
            a.obf = zbf; a.xbf_in = xbf; a.Dv = Dp + k * DM;
            mgemm<128, 2, 0><<<gFull, 256, 0, stream>>>(a);
        }
        {   // xbf += sig(res)*[(z@W1^T)*sigmoid(z@W2^T)]   (bf16 RMW)
            GemmArgs a = {};
            a.A = zbf; a.Wa = W1b + (size_t)k * DM * DM; a.Wb = W2b + (size_t)k * DM * DM;
            a.K = DM; a.N = DM;
            a.obf = xbf; a.xbf_in = xbf; a.resp = res; a.layer = k;
            mgemm<128, 3, 1><<<gFull, 256, 0, stream>>>(a);
        }
    }
    {   // decoder: out = x @ dec^T
        GemmArgs a = {};
        a.A = xbf; a.Wa = decb; a.K = DM; a.N = 64;
        a.of32 = out;
        mgemm<64, 4, 0><<<dim3(MROWS / 128, 1), 256, 0, stream>>>(a);
    }
}